// Round 6
// baseline (1131.549 us; speedup 1.0000x reference)
//
#include <hip/hip_runtime.h>

#define KNN 16
static constexpr int BB = 16;
static constexpr float LEAK = 0.2f;
static constexpr float EPSV = 1e-5f;
typedef unsigned long long u64;

// ---------------- branch-free bitonic top-16 primitives -------------------
__device__ __forceinline__ void ce_asc(u64 &a, u64 &b) {
  u64 x = a, y = b; bool sw = y < x; a = sw ? y : x; b = sw ? x : y;
}
__device__ __forceinline__ void ce_desc(u64 &a, u64 &b) {
  u64 x = a, y = b; bool sw = x < y; a = sw ? y : x; b = sw ? x : y;
}
__device__ __forceinline__ void bitonic_sort16(u64 *T) {
#pragma unroll
  for (int k = 2; k <= 16; k <<= 1) {
#pragma unroll
    for (int j = k >> 1; j > 0; j >>= 1) {
#pragma unroll
      for (int i = 0; i < 16; ++i) {
        int l = i ^ j;
        if (l > i) {
          if ((i & k) == 0) ce_asc(T[i], T[l]); else ce_desc(T[i], T[l]);
        }
      }
    }
  }
}
// R asc, T asc -> R = 16 smallest of union, sorted asc
__device__ __forceinline__ void merge_sorted16(u64 *R, const u64 *T) {
#pragma unroll
  for (int i = 0; i < 16; ++i) {
    u64 t = T[15 - i];
    R[i] = t < R[i] ? t : R[i];
  }
#pragma unroll
  for (int j = 8; j > 0; j >>= 1) {
#pragma unroll
    for (int i = 0; i < 16; ++i) {
      int l = i ^ j;
      if (l > i) ce_asc(R[i], R[l]);
    }
  }
}

// load KC sorted lists for row i and merge to final top-16 (ascending)
template<int KC>
__device__ __forceinline__ void merge_row(const u64* __restrict__ p, u64* R) {
#pragma unroll
  for (int s = 0; s < 16; ++s) R[s] = p[s];
#pragma unroll
  for (int c = 1; c < KC; ++c) {
    u64 T[16];
#pragma unroll
    for (int s = 0; s < 16; ++s) T[s] = p[(size_t)c*KNN + s];
    merge_sorted16(R, T);
  }
}

// ---------------- device: f0 = w_in @ coor + b_in -------------------------
__device__ __forceinline__ void f0_dev(const float* __restrict__ x,
    const float* __restrict__ w_in, const float* __restrict__ b_in,
    float* __restrict__ f0, int bid) {
  int i = bid * 256 + threadIdx.x;
  float px = x[i*3+0], py = x[i*3+1], pz = x[i*3+2];
#pragma unroll
  for (int o = 0; o < 8; ++o) {
    f0[i*8+o] = w_in[o*3+0]*px + w_in[o*3+1]*py + w_in[o*3+2]*pz + b_in[o];
  }
}

// ---------------- device: kNN split-K partial top-16 ----------------------
__device__ void knn_part_dev(const float* __restrict__ qxyz, int Nq,
    const float* __restrict__ kxyz, int Nk, int KC, u64* __restrict__ part,
    int bid) {
  __shared__ float4 keys[1024];
  int nqb = (Nq + 255) >> 8;
  int c  = bid % KC;
  int qb = (bid / KC) % nqb;
  int b  = bid / (KC * nqb);
  int nkc = Nk / KC;
  int kbase = c * nkc;
  for (int j = threadIdx.x; j < nkc; j += 256) {
    const float* kp = kxyz + (size_t)(b*Nk + kbase + j)*3;
    float kx = kp[0], ky = kp[1], kz = kp[2];
    keys[j] = make_float4(kx, ky, kz, kx*kx + ky*ky + kz*kz);
  }
  __syncthreads();
  int q = (qb << 8) + threadIdx.x;
  if (q >= Nq) return;
  const float* qp = qxyz + (size_t)(b*Nq + q)*3;
  float qx = qp[0], qy = qp[1], qz = qp[2];
  float q2 = qx*qx + qy*qy + qz*qz;
  u64 R[16];
#pragma unroll
  for (int s = 0; s < 16; ++s) R[s] = 0xFFFFFFFFFFFFFFFFull;
  for (int j0 = 0; j0 < nkc; j0 += 16) {
    u64 T[16];
#pragma unroll
    for (int u = 0; u < 16; ++u) {
      float4 kk = keys[j0 + u];
      float qk = qx*kk.x + qy*kk.y + qz*kk.z;
      float d2 = q2 + kk.w - 2.0f*qk;
      int bb = __float_as_int(d2);
      unsigned k32 = (unsigned)bb ^ (unsigned)((bb >> 31) | 0x80000000);
      T[u] = ((u64)k32 << 32) | (unsigned)(kbase + j0 + u);
    }
    bitonic_sort16(T);
    merge_sorted16(R, T);
  }
  u64* op = part + ((size_t)(b*Nq + q)*KC + c)*KNN;
#pragma unroll
  for (int s = 0; s < KNN; ++s) op[s] = R[s];
}

// ---------------- device: segmented FPS (packed-u64 DPP argmax) -----------
__device__ __forceinline__ u64 fps_max64(u64 a, u64 b) { return a > b ? a : b; }
template<int CTRL>
__device__ __forceinline__ u64 fps_dpp_u64(u64 v) {
  unsigned lo = (unsigned)__builtin_amdgcn_update_dpp(0, (int)(unsigned)(v & 0xFFFFFFFFull),
                                                      CTRL, 0xF, 0xF, false);
  unsigned hi = (unsigned)__builtin_amdgcn_update_dpp(0, (int)(unsigned)(v >> 32),
                                                      CTRL, 0xF, 0xF, false);
  return ((u64)hi << 32) | lo;
}
template<int P>
__device__ void fps_seg_dev(const float* __restrict__ xyz, int np,
    int t0, int t1, int* __restrict__ fidx,
    float* __restrict__ g_dl, int* __restrict__ g_far, int b) {
  constexpr int NN = P * 256;
  __shared__ float sx[NN], sy[NN], sz[NN];
  __shared__ u64 s_key[2][4];
  int tid = threadIdx.x;
  float px[P], py[P], pz[P], dl[P];
#pragma unroll
  for (int i = 0; i < P; ++i) {
    int p = tid + (i << 8);
    const float* pp = xyz + (size_t)(b*NN + p)*3;
    px[i] = pp[0]; py[i] = pp[1]; pz[i] = pp[2];
    sx[p] = px[i]; sy[p] = py[i]; sz[p] = pz[i];
  }
  int far;
  if (t0 == 0) {
#pragma unroll
    for (int i = 0; i < P; ++i) dl[i] = 1e10f;
    far = 0;
  } else {
#pragma unroll
    for (int i = 0; i < P; ++i) dl[i] = g_dl[b*NN + tid + (i << 8)];
    far = g_far[b];
  }
  __syncthreads();
  for (int t = t0; t < t1; ++t) {
    if (tid == 0) fidx[b*np + t] = far;
    float cx = sx[far], cy = sy[far], cz = sz[far];
    float bv = -1.0f; int bi = 0;
#pragma unroll
    for (int i = 0; i < P; ++i) {
      float dx = __fsub_rn(px[i], cx);
      float dy = __fsub_rn(py[i], cy);
      float dz = __fsub_rn(pz[i], cz);
      float d = __fadd_rn(__fadd_rn(__fmul_rn(dx,dx), __fmul_rn(dy,dy)), __fmul_rn(dz,dz));
      dl[i] = fminf(dl[i], d);
      if (dl[i] > bv) { bv = dl[i]; bi = tid + (i << 8); }
    }
    u64 k = ((u64)__float_as_uint(bv) << 32) | (unsigned)(~bi);
    k = fps_max64(k, fps_dpp_u64<0x111>(k));
    k = fps_max64(k, fps_dpp_u64<0x112>(k));
    k = fps_max64(k, fps_dpp_u64<0x114>(k));
    k = fps_max64(k, fps_dpp_u64<0x118>(k));
    k = fps_max64(k, fps_dpp_u64<0x142>(k));
    k = fps_max64(k, fps_dpp_u64<0x143>(k));
    unsigned wlo = (unsigned)__builtin_amdgcn_readlane((int)(unsigned)(k & 0xFFFFFFFFull), 63);
    unsigned whi = (unsigned)__builtin_amdgcn_readlane((int)(unsigned)(k >> 32), 63);
    int buf = t & 1;
    if ((tid & 63) == 0)
      s_key[buf][tid >> 6] = ((u64)whi << 32) | wlo;
    __syncthreads();
    u64 best = s_key[buf][0];
    best = fps_max64(best, s_key[buf][1]);
    best = fps_max64(best, s_key[buf][2]);
    best = fps_max64(best, s_key[buf][3]);
    far = (int)(~(unsigned)(best & 0xFFFFFFFFull));
  }
#pragma unroll
  for (int i = 0; i < P; ++i) g_dl[b*NN + tid + (i << 8)] = dl[i];
  if (tid == 0) g_far[b] = far;
}

// ---------------- device: GN stats with inline merge + inline base --------
// block = (b, g, os, ch); thread = one q row. pp[(b*4+g)*8 + os*NCH + ch]
template<int C, int O, int KC, int NCH, int OSPLIT>
__device__ void stats_dev(const float* __restrict__ fsrc, int Nsrc,
    const float* __restrict__ fq, int Nq, const u64* __restrict__ part,
    const float* __restrict__ w, double2* __restrict__ pp, int bid) {
  constexpr int Og = O / 4;
  constexpr int Os = Og / OSPLIT;
  __shared__ float wl[Os * C], wd[Os * C];
  __shared__ double rs[256], rs2[256];
  constexpr int UNIT = NCH * OSPLIT;
  int bg = bid / UNIT, r = bid % UNIT;
  int ch = r % NCH, os = r / NCH;
  int b = bg >> 2, g = bg & 3;
  int tid = threadIdx.x;
  int obase = g*Og + os*Os;
  for (int t = tid; t < Os * C; t += 256) {
    int oo = t / C, c = t % C;
    const float* wr = w + (size_t)(obase + oo)*2*C;
    wl[t] = wr[c];
    wd[t] = wr[C + c] - wr[c];
  }
  __syncthreads();
  double s = 0.0, s2 = 0.0;
  int q = ch*256 + tid;
  if (q < Nq) {
    const u64* p = part + (size_t)(b*Nq + q)*KC*KNN;
    u64 R[16];
    merge_row<KC>(p, R);
    float bs[Os];
    {
      float fqr[C];
      const float4* f4 = (const float4*)(fq + (size_t)(b*Nq + q)*C);
#pragma unroll
      for (int c4 = 0; c4 < C/4; ++c4) {
        float4 v = f4[c4];
        fqr[c4*4+0]=v.x; fqr[c4*4+1]=v.y; fqr[c4*4+2]=v.z; fqr[c4*4+3]=v.w;
      }
#pragma unroll
      for (int oo = 0; oo < Os; ++oo) {
        float a = 0.f;
#pragma unroll
        for (int c = 0; c < C; ++c) a += wd[oo*C + c] * fqr[c];
        bs[oo] = a;
      }
    }
    for (int k = 0; k < KNN; ++k) {
      int src = (int)(unsigned)(R[k] & 0xFFFFFFFFu);
      float ftl[C];
      const float4* f4 = (const float4*)(fsrc + (size_t)(b*Nsrc + src)*C);
#pragma unroll
      for (int c4 = 0; c4 < C/4; ++c4) {
        float4 v = f4[c4];
        ftl[c4*4+0]=v.x; ftl[c4*4+1]=v.y; ftl[c4*4+2]=v.z; ftl[c4*4+3]=v.w;
      }
#pragma unroll
      for (int oo = 0; oo < Os; ++oo) {
        float acc = bs[oo];
#pragma unroll
        for (int c = 0; c < C; ++c) acc += wl[oo*C + c] * ftl[c];
        s += acc;
        s2 += (double)acc * (double)acc;
      }
    }
  }
  rs[tid] = s; rs2[tid] = s2;
  __syncthreads();
  for (int off = 128; off > 0; off >>= 1) {
    if (tid < off) { rs[tid] += rs[tid+off]; rs2[tid] += rs2[tid+off]; }
    __syncthreads();
  }
  if (tid == 0) pp[(size_t)bg*8 + os*NCH + ch] = make_double2(rs[0], rs2[0]);
}

// ---------------- device: finalize (inline merge + base + GN + max) -------
template<int C, int O, int QB, int KC, int NP>
__device__ void fin_dev(const float* __restrict__ fsrc, int Nsrc,
    const float* __restrict__ fq, int Nq, const u64* __restrict__ part,
    const float* __restrict__ w, const double2* __restrict__ pp,
    const float* __restrict__ gamma, const float* __restrict__ beta,
    float* __restrict__ fout, int bid) {
  constexpr int Og = O / 4;
  constexpr int C4 = C / 4;
  __shared__ float ft[QB][KNN][C];
  __shared__ float fqs[QB][C];
  __shared__ int s_idx[QB][KNN];
  __shared__ float s_mu[4], s_rsv[4];
  int tid = threadIdx.x;
  int nb = Nq / QB;
  int b = bid / nb;
  int q0 = (bid % nb) * QB;
  if (tid < QB) {
    const u64* p = part + (size_t)(b*Nq + q0 + tid)*KC*KNN;
    u64 R[16];
    merge_row<KC>(p, R);
#pragma unroll
    for (int s = 0; s < 16; ++s) s_idx[tid][s] = (int)(unsigned)(R[s] & 0xFFFFFFFFu);
  } else if (tid >= 32 && tid < 36) {
    int g = tid - 32;
    double s = 0.0, s2 = 0.0;
#pragma unroll
    for (int p = 0; p < NP; ++p) {
      double2 v = pp[(size_t)(b*4 + g)*8 + p];
      s += v.x; s2 += v.y;
    }
    double cnt = (double)Og * (double)Nq * (double)KNN;
    double mu = s / cnt;
    double var = s2 / cnt - mu*mu;
    s_mu[g] = (float)mu;
    s_rsv[g] = 1.0f / sqrtf((float)var + EPSV);
  } else if (tid >= 64 && tid < 64 + QB*C4) {
    int t = tid - 64;
    int ql = t / C4, c4 = t % C4;
    ((float4*)&fqs[ql][0])[c4] = ((const float4*)(fq + (size_t)(b*Nq + q0 + ql)*C))[c4];
  }
  __syncthreads();
  for (int v = tid; v < QB*KNN*C4; v += 256) {
    int row = v / C4, c4 = v % C4;
    int ql = row / KNN, k = row % KNN;
    int src = s_idx[ql][k];
    ((float4*)&ft[ql][k][0])[c4] = ((const float4*)(fsrc + (size_t)(b*Nsrc + src)*C))[c4];
  }
  __syncthreads();
  int ql = tid / O, o = tid % O;
  int g = o / Og;
  float mu = s_mu[g], rsv = s_rsv[g];
  float ga = gamma[o], be = beta[o];
  float4 wr4[C4];
  float bs = 0.f;
  const float4* wp4 = (const float4*)(w + (size_t)o*2*C);
#pragma unroll
  for (int c4 = 0; c4 < C4; ++c4) {
    float4 lo = wp4[c4], hi = wp4[C4 + c4];
    float4 fv = ((const float4*)&fqs[ql][0])[c4];
    bs += (hi.x - lo.x) * fv.x;
    bs += (hi.y - lo.y) * fv.y;
    bs += (hi.z - lo.z) * fv.z;
    bs += (hi.w - lo.w) * fv.w;
    wr4[c4] = lo;
  }
  float m = -3.4e38f;
  for (int k = 0; k < KNN; ++k) {
    float acc = bs;
    const float4* fv = (const float4*)&ft[ql][k][0];
#pragma unroll
    for (int c4 = 0; c4 < C4; ++c4) {
      float4 v = fv[c4];
      acc += wr4[c4].x*v.x; acc += wr4[c4].y*v.y;
      acc += wr4[c4].z*v.z; acc += wr4[c4].w*v.w;
    }
    float xn = (acc - mu) * rsv;
    float yv = xn*ga + be;
    yv = yv > 0.f ? yv : LEAK*yv;
    m = fmaxf(m, yv);
  }
  fout[(size_t)(b*Nq + q0 + ql)*O + o] = m;
}

// ---------------- gather coor_q / f_q by FPS indices ----------------------
__global__ __launch_bounds__(256) void gather_kernel(const float* __restrict__ coor,
    const float* __restrict__ f, int Nsrc, int C, const int* __restrict__ fidx,
    int np, float* __restrict__ coor_q, float* __restrict__ f_q) {
  int i = blockIdx.x * 256 + threadIdx.x;
  if (i >= BB * np) return;
  int b = i / np;
  int src = fidx[i];
  const float* cs = coor + (size_t)(b*Nsrc + src)*3;
  coor_q[i*3+0] = cs[0]; coor_q[i*3+1] = cs[1]; coor_q[i*3+2] = cs[2];
  const float* fs = f + (size_t)(b*Nsrc + src)*C;
  float* fd = f_q + (size_t)i*C;
  for (int c = 0; c < C; ++c) fd[c] = fs[c];
}

// ---------------- fused dispatches ----------------------------------------
__global__ __launch_bounds__(256) void fusedA_kernel(const float* __restrict__ x,
    const float* __restrict__ w_in, const float* __restrict__ b_in,
    float* __restrict__ f0, u64* __restrict__ part, int* __restrict__ fidx1,
    float* __restrict__ g_dl, int* __restrict__ g_far) {
  int bid = blockIdx.x;
  if (bid < 16)       fps_seg_dev<8>(x, 512, 0, 170, fidx1, g_dl, g_far, bid);
  else if (bid < 528) knn_part_dev(x, 2048, x, 2048, 4, part, bid - 16);
  else                f0_dev(x, w_in, b_in, f0, bid - 528);
}

__global__ __launch_bounds__(256) void fusedS1_kernel(const float* __restrict__ x,
    int* __restrict__ fidx1, float* __restrict__ g_dl, int* __restrict__ g_far,
    const float* __restrict__ f0, const u64* __restrict__ part,
    const float* __restrict__ w1, double2* __restrict__ pp) {
  int bid = blockIdx.x;
  if (bid < 16) fps_seg_dev<8>(x, 512, 170, 341, fidx1, g_dl, g_far, bid);
  else          stats_dev<8,32,4,8,1>(f0, 2048, f0, 2048, part, w1, pp, bid - 16);
}

__global__ __launch_bounds__(256) void fusedF1_kernel(const float* __restrict__ x,
    int* __restrict__ fidx1, float* __restrict__ g_dl, int* __restrict__ g_far,
    const float* __restrict__ f0, const u64* __restrict__ part,
    const float* __restrict__ w1, const double2* __restrict__ pp,
    const float* __restrict__ g1, const float* __restrict__ be1,
    float* __restrict__ f1) {
  int bid = blockIdx.x;
  if (bid < 16) fps_seg_dev<8>(x, 512, 341, 512, fidx1, g_dl, g_far, bid);
  else          fin_dev<8,32,8,4,8>(f0, 2048, f0, 2048, part, w1, pp, g1, be1, f1, bid - 16);
}

__global__ __launch_bounds__(256) void fusedB_kernel(const float* __restrict__ cq1,
    const float* __restrict__ x, u64* __restrict__ part2, u64* __restrict__ part3,
    int* __restrict__ fidx2, float* __restrict__ g_dl, int* __restrict__ g_far) {
  int bid = blockIdx.x;
  if (bid < 16)       fps_seg_dev<2>(cq1, 128, 0, 64, fidx2, g_dl, g_far, bid);
  else if (bid < 272) knn_part_dev(cq1, 512, x, 2048, 8, part2, bid - 16);
  else                knn_part_dev(cq1, 512, cq1, 512, 8, part3, bid - 272);
}

__global__ __launch_bounds__(256) void fusedS2_kernel(const float* __restrict__ cq1,
    int* __restrict__ fidx2, float* __restrict__ g_dl, int* __restrict__ g_far,
    const float* __restrict__ f1, const float* __restrict__ fq1,
    const u64* __restrict__ part2, const float* __restrict__ w2,
    double2* __restrict__ pp) {
  int bid = blockIdx.x;
  if (bid < 16) fps_seg_dev<2>(cq1, 128, 64, 128, fidx2, g_dl, g_far, bid);
  else          stats_dev<32,64,8,2,2>(f1, 2048, fq1, 512, part2, w2, pp, bid - 16);
}

__global__ __launch_bounds__(256) void fin2_kernel(const float* __restrict__ f1,
    const float* __restrict__ fq1, const u64* __restrict__ part2,
    const float* __restrict__ w2, const double2* __restrict__ pp,
    const float* __restrict__ g2, const float* __restrict__ be2,
    float* __restrict__ f2) {
  fin_dev<32,64,4,8,4>(f1, 2048, fq1, 512, part2, w2, pp, g2, be2, f2, blockIdx.x);
}

__global__ __launch_bounds__(256) void stats3_kernel(const float* __restrict__ f2,
    const u64* __restrict__ part3, const float* __restrict__ w3,
    double2* __restrict__ pp) {
  stats_dev<64,64,8,2,2>(f2, 512, f2, 512, part3, w3, pp, blockIdx.x);
}

__global__ __launch_bounds__(256) void fin3_kernel(const float* __restrict__ f2,
    const u64* __restrict__ part3, const float* __restrict__ w3,
    const double2* __restrict__ pp, const float* __restrict__ g3,
    const float* __restrict__ be3, float* __restrict__ f3) {
  fin_dev<64,64,4,8,4>(f2, 512, f2, 512, part3, w3, pp, g3, be3, f3, blockIdx.x);
}

__global__ __launch_bounds__(256) void knn4_kernel(const float* __restrict__ cq2,
    const float* __restrict__ cq1, u64* __restrict__ part) {
  knn_part_dev(cq2, 128, cq1, 512, 8, part, blockIdx.x);
}

__global__ __launch_bounds__(256) void stats4_kernel(const float* __restrict__ f3,
    const float* __restrict__ fq2, const u64* __restrict__ part,
    const float* __restrict__ w4, double2* __restrict__ pp) {
  stats_dev<64,128,8,1,4>(f3, 512, fq2, 128, part, w4, pp, blockIdx.x);
}

__global__ __launch_bounds__(256) void fin4_kernel(const float* __restrict__ f3,
    const float* __restrict__ fq2, const u64* __restrict__ part,
    const float* __restrict__ w4, const double2* __restrict__ pp,
    const float* __restrict__ g4, const float* __restrict__ be4,
    float* __restrict__ f4) {
  fin_dev<64,128,2,8,4>(f3, 512, fq2, 128, part, w4, pp, g4, be4, f4, blockIdx.x);
}

extern "C" void kernel_launch(void* const* d_in, const int* in_sizes, int n_in,
                              void* d_out, int out_size, void* d_ws, size_t ws_size,
                              hipStream_t stream) {
  const float* x    = (const float*)d_in[0];
  const float* w_in = (const float*)d_in[3];
  const float* b_in = (const float*)d_in[4];
  const float* w1 = (const float*)d_in[5];
  const float* g1 = (const float*)d_in[6];
  const float* be1= (const float*)d_in[7];
  const float* w2 = (const float*)d_in[8];
  const float* g2 = (const float*)d_in[9];
  const float* be2= (const float*)d_in[10];
  const float* w3 = (const float*)d_in[11];
  const float* g3 = (const float*)d_in[12];
  const float* be3= (const float*)d_in[13];
  const float* w4 = (const float*)d_in[14];
  const float* g4 = (const float*)d_in[15];
  const float* be4= (const float*)d_in[16];
  float* out = (float*)d_out;
  (void)in_sizes; (void)n_in; (void)out_size; (void)ws_size;

  char* ws = (char*)d_ws;
  size_t off = 0;
  auto alloc = [&](size_t count) {        // count in 4-byte units
    void* p = ws + off;
    off += (count * 4 + 255) & ~(size_t)255;
    return p;
  };
  float* f0    = (float*)alloc(16*2048*8);
  float* f1    = (float*)alloc(16*2048*32);
  float* f2    = (float*)alloc(16*512*64);
  float* f3    = (float*)alloc(16*512*64);
  float* fq1   = (float*)alloc(16*512*32);
  float* fq2   = (float*)alloc(16*128*64);
  float* cq1   = (float*)alloc(16*512*3);
  double2* pp  = (double2*)alloc(64*8*4);
  int* fidx1   = (int*)alloc(16*512);
  int* fidx2   = (int*)alloc(16*128);
  float* g_dl1 = (float*)alloc(16*2048);
  int* g_far1  = (int*)alloc(16);
  float* g_dl2 = (float*)alloc(16*512);
  int* g_far2  = (int*)alloc(16);
  u64* part    = (u64*)alloc(2 * 16*2048*4*16);   // 16 MB (2M u64)
  u64* partB   = part + (size_t)16*512*8*16;      // 8 MB offset for knn3

  float* cq2 = out;              // (16,128,3)
  float* f4  = out + 16*128*3;   // (16,128,128)

  // ---- layer 1: knn1(KC=4) + f0 + fps1 segments riding every dispatch ----
  fusedA_kernel<<<656, 256, 0, stream>>>(x, w_in, b_in, f0, part, fidx1, g_dl1, g_far1);
  fusedS1_kernel<<<528, 256, 0, stream>>>(x, fidx1, g_dl1, g_far1, f0, part, w1, pp);
  fusedF1_kernel<<<4112, 256, 0, stream>>>(x, fidx1, g_dl1, g_far1, f0, part, w1, pp, g1, be1, f1);
  gather_kernel<<<32, 256, 0, stream>>>(x, f1, 2048, 32, fidx1, 512, cq1, fq1);

  // ---- layers 2+3 knn + fps2 ----
  fusedB_kernel<<<528, 256, 0, stream>>>(cq1, x, part, partB, fidx2, g_dl2, g_far2);
  fusedS2_kernel<<<272, 256, 0, stream>>>(cq1, fidx2, g_dl2, g_far2, f1, fq1, part, w2, pp);
  fin2_kernel<<<2048, 256, 0, stream>>>(f1, fq1, part, w2, pp, g2, be2, f2);

  // ---- layer 3 ----
  stats3_kernel<<<256, 256, 0, stream>>>(f2, partB, w3, pp);
  fin3_kernel<<<2048, 256, 0, stream>>>(f2, partB, w3, pp, g3, be3, f3);
  gather_kernel<<<8, 256, 0, stream>>>(cq1, f3, 512, 64, fidx2, 128, cq2, fq2);

  // ---- layer 4 ----
  knn4_kernel<<<128, 256, 0, stream>>>(cq2, cq1, part);
  stats4_kernel<<<256, 256, 0, stream>>>(f3, fq2, part, w4, pp);
  fin4_kernel<<<1024, 256, 0, stream>>>(f3, fq2, part, w4, pp, g4, be4, f4);
}

// Round 7
// 529.454 us; speedup vs baseline: 2.1372x; 2.1372x over previous
//
#include <hip/hip_runtime.h>

#define KNN 16
static constexpr int BB = 16;
static constexpr float LEAK = 0.2f;
static constexpr float EPSV = 1e-5f;
typedef unsigned long long u64;

// ---------------- branch-free bitonic top-16 primitives -------------------
__device__ __forceinline__ void ce_asc(u64 &a, u64 &b) {
  u64 x = a, y = b; bool sw = y < x; a = sw ? y : x; b = sw ? x : y;
}
__device__ __forceinline__ void ce_desc(u64 &a, u64 &b) {
  u64 x = a, y = b; bool sw = x < y; a = sw ? y : x; b = sw ? x : y;
}
__device__ __forceinline__ void bitonic_sort16(u64 *T) {
#pragma unroll
  for (int k = 2; k <= 16; k <<= 1) {
#pragma unroll
    for (int j = k >> 1; j > 0; j >>= 1) {
#pragma unroll
      for (int i = 0; i < 16; ++i) {
        int l = i ^ j;
        if (l > i) {
          if ((i & k) == 0) ce_asc(T[i], T[l]); else ce_desc(T[i], T[l]);
        }
      }
    }
  }
}
// R asc, T asc -> R = 16 smallest of union, sorted asc
__device__ __forceinline__ void merge_sorted16(u64 *R, const u64 *T) {
#pragma unroll
  for (int i = 0; i < 16; ++i) {
    u64 t = T[15 - i];
    R[i] = t < R[i] ? t : R[i];
  }
#pragma unroll
  for (int j = 8; j > 0; j >>= 1) {
#pragma unroll
    for (int i = 0; i < 16; ++i) {
      int l = i ^ j;
      if (l > i) ce_asc(R[i], R[l]);
    }
  }
}

template<int KC>
__device__ __forceinline__ void merge_row(const u64* __restrict__ p, u64* R) {
#pragma unroll
  for (int s = 0; s < 16; ++s) R[s] = p[s];
#pragma unroll
  for (int c = 1; c < KC; ++c) {
    u64 T[16];
#pragma unroll
    for (int s = 0; s < 16; ++s) T[s] = p[(size_t)c*KNN + s];
    merge_sorted16(R, T);
  }
}

// ---------------- device: f0 = w_in @ coor + b_in -------------------------
__device__ __forceinline__ void f0_dev(const float* __restrict__ x,
    const float* __restrict__ w_in, const float* __restrict__ b_in,
    float* __restrict__ f0, int bid) {
  int i = bid * 256 + threadIdx.x;
  float px = x[i*3+0], py = x[i*3+1], pz = x[i*3+2];
#pragma unroll
  for (int o = 0; o < 8; ++o) {
    f0[i*8+o] = w_in[o*3+0]*px + w_in[o*3+1]*py + w_in[o*3+2]*pz + b_in[o];
  }
}

// ---------------- device: kNN split-K partial top-16 ----------------------
__device__ void knn_part_dev(const float* __restrict__ qxyz, int Nq,
    const float* __restrict__ kxyz, int Nk, int KC, u64* __restrict__ part,
    int bid) {
  __shared__ float4 keys[1024];
  int nqb = (Nq + 255) >> 8;
  int c  = bid % KC;
  int qb = (bid / KC) % nqb;
  int b  = bid / (KC * nqb);
  int nkc = Nk / KC;
  int kbase = c * nkc;
  for (int j = threadIdx.x; j < nkc; j += 256) {
    const float* kp = kxyz + (size_t)(b*Nk + kbase + j)*3;
    float kx = kp[0], ky = kp[1], kz = kp[2];
    keys[j] = make_float4(kx, ky, kz, kx*kx + ky*ky + kz*kz);
  }
  __syncthreads();
  int q = (qb << 8) + threadIdx.x;
  if (q >= Nq) return;
  const float* qp = qxyz + (size_t)(b*Nq + q)*3;
  float qx = qp[0], qy = qp[1], qz = qp[2];
  float q2 = qx*qx + qy*qy + qz*qz;
  u64 R[16];
#pragma unroll
  for (int s = 0; s < 16; ++s) R[s] = 0xFFFFFFFFFFFFFFFFull;
  for (int j0 = 0; j0 < nkc; j0 += 16) {
    u64 T[16];
#pragma unroll
    for (int u = 0; u < 16; ++u) {
      float4 kk = keys[j0 + u];
      float qk = qx*kk.x + qy*kk.y + qz*kk.z;
      float d2 = q2 + kk.w - 2.0f*qk;
      int bb = __float_as_int(d2);
      unsigned k32 = (unsigned)bb ^ (unsigned)((bb >> 31) | 0x80000000);
      T[u] = ((u64)k32 << 32) | (unsigned)(kbase + j0 + u);
    }
    bitonic_sort16(T);
    merge_sorted16(R, T);
  }
  u64* op = part + ((size_t)(b*Nq + q)*KC + c)*KNN;
#pragma unroll
  for (int s = 0; s < KNN; ++s) op[s] = R[s];
}

// ---------------- device: segmented FPS (packed-u64 DPP argmax) -----------
__device__ __forceinline__ u64 fps_max64(u64 a, u64 b) { return a > b ? a : b; }
template<int CTRL>
__device__ __forceinline__ u64 fps_dpp_u64(u64 v) {
  unsigned lo = (unsigned)__builtin_amdgcn_update_dpp(0, (int)(unsigned)(v & 0xFFFFFFFFull),
                                                      CTRL, 0xF, 0xF, false);
  unsigned hi = (unsigned)__builtin_amdgcn_update_dpp(0, (int)(unsigned)(v >> 32),
                                                      CTRL, 0xF, 0xF, false);
  return ((u64)hi << 32) | lo;
}
template<int P>
__device__ void fps_seg_dev(const float* __restrict__ xyz, int np,
    int t0, int t1, int* __restrict__ fidx,
    float* __restrict__ g_dl, int* __restrict__ g_far, int b) {
  constexpr int NN = P * 256;
  __shared__ float sx[NN], sy[NN], sz[NN];
  __shared__ u64 s_key[2][4];
  int tid = threadIdx.x;
  float px[P], py[P], pz[P], dl[P];
#pragma unroll
  for (int i = 0; i < P; ++i) {
    int p = tid + (i << 8);
    const float* pp = xyz + (size_t)(b*NN + p)*3;
    px[i] = pp[0]; py[i] = pp[1]; pz[i] = pp[2];
    sx[p] = px[i]; sy[p] = py[i]; sz[p] = pz[i];
  }
  int far;
  if (t0 == 0) {
#pragma unroll
    for (int i = 0; i < P; ++i) dl[i] = 1e10f;
    far = 0;
  } else {
#pragma unroll
    for (int i = 0; i < P; ++i) dl[i] = g_dl[b*NN + tid + (i << 8)];
    far = g_far[b];
  }
  __syncthreads();
  for (int t = t0; t < t1; ++t) {
    if (tid == 0) fidx[b*np + t] = far;
    float cx = sx[far], cy = sy[far], cz = sz[far];
    float bv = -1.0f; int bi = 0;
#pragma unroll
    for (int i = 0; i < P; ++i) {
      float dx = __fsub_rn(px[i], cx);
      float dy = __fsub_rn(py[i], cy);
      float dz = __fsub_rn(pz[i], cz);
      float d = __fadd_rn(__fadd_rn(__fmul_rn(dx,dx), __fmul_rn(dy,dy)), __fmul_rn(dz,dz));
      dl[i] = fminf(dl[i], d);
      if (dl[i] > bv) { bv = dl[i]; bi = tid + (i << 8); }
    }
    u64 k = ((u64)__float_as_uint(bv) << 32) | (unsigned)(~bi);
    k = fps_max64(k, fps_dpp_u64<0x111>(k));
    k = fps_max64(k, fps_dpp_u64<0x112>(k));
    k = fps_max64(k, fps_dpp_u64<0x114>(k));
    k = fps_max64(k, fps_dpp_u64<0x118>(k));
    k = fps_max64(k, fps_dpp_u64<0x142>(k));
    k = fps_max64(k, fps_dpp_u64<0x143>(k));
    unsigned wlo = (unsigned)__builtin_amdgcn_readlane((int)(unsigned)(k & 0xFFFFFFFFull), 63);
    unsigned whi = (unsigned)__builtin_amdgcn_readlane((int)(unsigned)(k >> 32), 63);
    int buf = t & 1;
    if ((tid & 63) == 0)
      s_key[buf][tid >> 6] = ((u64)whi << 32) | wlo;
    __syncthreads();
    u64 best = s_key[buf][0];
    best = fps_max64(best, s_key[buf][1]);
    best = fps_max64(best, s_key[buf][2]);
    best = fps_max64(best, s_key[buf][3]);
    far = (int)(~(unsigned)(best & 0xFFFFFFFFull));
  }
#pragma unroll
  for (int i = 0; i < P; ++i) g_dl[b*NN + tid + (i << 8)] = dl[i];
  if (tid == 0) g_far[b] = far;
}

// ---------------- device: conv + fused GN stats + minmax over k ----------
// block covers QB q-rows; threads (ql,o). Writes ymax/ymin per (q,o) and
// per-block per-group (sum, sumsq) partials pp1[(b*NB+chunk)*4+g].
template<int C, int O, int QB, int KC, int NB>
__device__ void conv_dev(const float* __restrict__ fsrc, int Nsrc,
    const float* __restrict__ fq, int Nq, const u64* __restrict__ part,
    const float* __restrict__ w, float* __restrict__ ym, float* __restrict__ yn,
    double2* __restrict__ pp1, int bid) {
  constexpr int Og = O / 4;
  constexpr int C4 = C / 4;
  __shared__ float ft[QB][KNN][C];
  __shared__ float fqs[QB][C];
  __shared__ int s_idx[QB][KNN];
  __shared__ double rs[256], rs2[256];
  int tid = threadIdx.x;
  int chunk = bid % NB;
  int b = bid / NB;
  int q0 = chunk * QB;
  if (tid < QB) {
    const u64* p = part + (size_t)(b*Nq + q0 + tid)*KC*KNN;
    u64 R[16];
    merge_row<KC>(p, R);
#pragma unroll
    for (int s = 0; s < 16; ++s) s_idx[tid][s] = (int)(unsigned)(R[s] & 0xFFFFFFFFu);
  } else if (tid >= 64 && tid < 64 + QB*C4) {
    int t = tid - 64;
    int ql = t / C4, c4 = t % C4;
    ((float4*)&fqs[ql][0])[c4] = ((const float4*)(fq + (size_t)(b*Nq + q0 + ql)*C))[c4];
  }
  __syncthreads();
  for (int v = tid; v < QB*KNN*C4; v += 256) {
    int row = v / C4, c4 = v % C4;
    int ql = row / KNN, k = row % KNN;
    int src = s_idx[ql][k];
    ((float4*)&ft[ql][k][0])[c4] = ((const float4*)(fsrc + (size_t)(b*Nsrc + src)*C))[c4];
  }
  __syncthreads();
  int ql = tid / O, o = tid % O;
  float4 wr4[C4];
  float bs = 0.f;
  const float4* wp4 = (const float4*)(w + (size_t)o*2*C);
#pragma unroll
  for (int c4 = 0; c4 < C4; ++c4) {
    float4 lo = wp4[c4], hi = wp4[C4 + c4];
    float4 fv = ((const float4*)&fqs[ql][0])[c4];
    bs += (hi.x - lo.x) * fv.x;
    bs += (hi.y - lo.y) * fv.y;
    bs += (hi.z - lo.z) * fv.z;
    bs += (hi.w - lo.w) * fv.w;
    wr4[c4] = lo;
  }
  float mx = -3.4e38f, mn = 3.4e38f;
  double s = 0.0, s2 = 0.0;
  for (int k = 0; k < KNN; ++k) {
    float acc = bs;
    const float4* fv = (const float4*)&ft[ql][k][0];
#pragma unroll
    for (int c4 = 0; c4 < C4; ++c4) {
      float4 v = fv[c4];
      acc += wr4[c4].x*v.x; acc += wr4[c4].y*v.y;
      acc += wr4[c4].z*v.z; acc += wr4[c4].w*v.w;
    }
    mx = fmaxf(mx, acc);
    mn = fminf(mn, acc);
    s += acc;
    s2 += (double)acc * (double)acc;
  }
  size_t oidx = (size_t)(b*Nq + q0 + ql)*O + o;
  ym[oidx] = mx;
  yn[oidx] = mn;
  rs[tid] = s; rs2[tid] = s2;
  __syncthreads();
#pragma unroll
  for (int st = QB/2; st > 0; st >>= 1) {
    if (ql < st) { rs[tid] += rs[tid + st*O]; rs2[tid] += rs2[tid + st*O]; }
    __syncthreads();
  }
#pragma unroll
  for (int st = Og/2; st > 0; st >>= 1) {
    if (tid < O && (o % Og) < st) { rs[tid] += rs[tid + st]; rs2[tid] += rs2[tid + st]; }
    __syncthreads();
  }
  if (tid < O && (o % Og) == 0) {
    int g = o / Og;
    pp1[((size_t)b*NB + chunk)*4 + g] = make_double2(rs[tid], rs2[tid]);
  }
}

// ---------------- device: finalize (reduce partials, GN+lrelu from minmax)-
template<int O, int NB, int FCH, int NQ>
__device__ void fin_dev(const float* __restrict__ ym, const float* __restrict__ yn,
    const double2* __restrict__ pp1, const float* __restrict__ gamma,
    const float* __restrict__ beta, float* __restrict__ fout, int bid) {
  constexpr int Og = O / 4;
  __shared__ double red[64], red2[64];
  __shared__ float s_mu[4], s_rsv[4];
  int tid = threadIdx.x;
  int b = bid / FCH;
  int f = bid % FCH;
  if (tid < 64) {
    int g = tid >> 4, j = tid & 15;
    double s = 0.0, s2 = 0.0;
    for (int c = j; c < NB; c += 16) {
      double2 v = pp1[((size_t)b*NB + c)*4 + g];
      s += v.x; s2 += v.y;
    }
    red[tid] = s; red2[tid] = s2;
  }
  __syncthreads();
#pragma unroll
  for (int st = 8; st > 0; st >>= 1) {
    if (tid < 64 && (tid & 15) < st) { red[tid] += red[tid+st]; red2[tid] += red2[tid+st]; }
    __syncthreads();
  }
  if (tid < 4) {
    double cnt = (double)Og * (double)NQ * (double)KNN;
    double mu = red[tid*16] / cnt;
    double var = red2[tid*16] / cnt - mu*mu;
    s_mu[tid] = (float)mu;
    s_rsv[tid] = 1.0f / sqrtf((float)var + EPSV);
  }
  __syncthreads();
  constexpr int PER = NQ * O / FCH;
  int e0 = f * PER;
  for (int e = e0 + tid; e < e0 + PER; e += 256) {
    int q = e / O, o = e % O;
    int g = o / Og;
    size_t idx = (size_t)(b*NQ + q)*O + o;
    float ga = gamma[o], be = beta[o];
    float ysel = (ga >= 0.f) ? ym[idx] : yn[idx];
    float xn = (ysel - s_mu[g]) * s_rsv[g];
    float yv = xn*ga + be;
    yv = yv > 0.f ? yv : LEAK*yv;
    fout[idx] = yv;
  }
}

// ---------------- gather coor_q / f_q by FPS indices ----------------------
__global__ __launch_bounds__(256) void gather_kernel(const float* __restrict__ coor,
    const float* __restrict__ f, int Nsrc, int C, const int* __restrict__ fidx,
    int np, float* __restrict__ coor_q, float* __restrict__ f_q) {
  int i = blockIdx.x * 256 + threadIdx.x;
  if (i >= BB * np) return;
  int b = i / np;
  int src = fidx[i];
  const float* cs = coor + (size_t)(b*Nsrc + src)*3;
  coor_q[i*3+0] = cs[0]; coor_q[i*3+1] = cs[1]; coor_q[i*3+2] = cs[2];
  const float* fs = f + (size_t)(b*Nsrc + src)*C;
  float* fd = f_q + (size_t)i*C;
  for (int c = 0; c < C; ++c) fd[c] = fs[c];
}

// ---------------- dispatch wrappers ---------------------------------------
__global__ __launch_bounds__(256) void fusedA_kernel(const float* __restrict__ x,
    const float* __restrict__ w_in, const float* __restrict__ b_in,
    float* __restrict__ f0, u64* __restrict__ part, int* __restrict__ fidx1,
    float* __restrict__ g_dl, int* __restrict__ g_far) {
  int bid = blockIdx.x;
  if (bid < 16)       fps_seg_dev<8>(x, 512, 0, 256, fidx1, g_dl, g_far, bid);
  else if (bid < 528) knn_part_dev(x, 2048, x, 2048, 4, part, bid - 16);
  else                f0_dev(x, w_in, b_in, f0, bid - 528);
}

__global__ __launch_bounds__(256) void conv1_kernel(const float* __restrict__ x,
    int* __restrict__ fidx1, float* __restrict__ g_dl, int* __restrict__ g_far,
    const float* __restrict__ f0, const u64* __restrict__ part,
    const float* __restrict__ w1, float* __restrict__ ym, float* __restrict__ yn,
    double2* __restrict__ pp1) {
  int bid = blockIdx.x;
  if (bid < 16) fps_seg_dev<8>(x, 512, 256, 448, fidx1, g_dl, g_far, bid);
  else          conv_dev<8,32,8,4,256>(f0, 2048, f0, 2048, part, w1, ym, yn, pp1, bid - 16);
}

__global__ __launch_bounds__(256) void fin1_kernel(const float* __restrict__ x,
    int* __restrict__ fidx1, float* __restrict__ g_dl, int* __restrict__ g_far,
    const float* __restrict__ ym, const float* __restrict__ yn,
    const double2* __restrict__ pp1, const float* __restrict__ g1,
    const float* __restrict__ be1, float* __restrict__ f1) {
  int bid = blockIdx.x;
  if (bid < 16) fps_seg_dev<8>(x, 512, 448, 512, fidx1, g_dl, g_far, bid);
  else          fin_dev<32,256,32,2048>(ym, yn, pp1, g1, be1, f1, bid - 16);
}

__global__ __launch_bounds__(256) void fusedB_kernel(const float* __restrict__ cq1,
    const float* __restrict__ x, u64* __restrict__ part2, u64* __restrict__ part3,
    int* __restrict__ fidx2, float* __restrict__ g_dl, int* __restrict__ g_far) {
  int bid = blockIdx.x;
  if (bid < 16)       fps_seg_dev<2>(cq1, 128, 0, 64, fidx2, g_dl, g_far, bid);
  else if (bid < 272) knn_part_dev(cq1, 512, x, 2048, 8, part2, bid - 16);
  else                knn_part_dev(cq1, 512, cq1, 512, 8, part3, bid - 272);
}

__global__ __launch_bounds__(256) void conv2_kernel(const float* __restrict__ cq1,
    int* __restrict__ fidx2, float* __restrict__ g_dl, int* __restrict__ g_far,
    const float* __restrict__ f1, const float* __restrict__ fq1,
    const u64* __restrict__ part2, const float* __restrict__ w2,
    float* __restrict__ ym, float* __restrict__ yn, double2* __restrict__ pp1) {
  int bid = blockIdx.x;
  if (bid < 16) fps_seg_dev<2>(cq1, 128, 64, 128, fidx2, g_dl, g_far, bid);
  else          conv_dev<32,64,4,8,128>(f1, 2048, fq1, 512, part2, w2, ym, yn, pp1, bid - 16);
}

__global__ __launch_bounds__(256) void fin2_kernel(const float* __restrict__ ym,
    const float* __restrict__ yn, const double2* __restrict__ pp1,
    const float* __restrict__ g2, const float* __restrict__ be2,
    float* __restrict__ f2) {
  fin_dev<64,128,16,512>(ym, yn, pp1, g2, be2, f2, blockIdx.x);
}

__global__ __launch_bounds__(256) void conv3_kernel(const float* __restrict__ f2,
    const u64* __restrict__ part3, const float* __restrict__ w3,
    float* __restrict__ ym, float* __restrict__ yn, double2* __restrict__ pp1) {
  conv_dev<64,64,4,8,128>(f2, 512, f2, 512, part3, w3, ym, yn, pp1, blockIdx.x);
}

__global__ __launch_bounds__(256) void fin3_kernel(const float* __restrict__ ym,
    const float* __restrict__ yn, const double2* __restrict__ pp1,
    const float* __restrict__ g3, const float* __restrict__ be3,
    float* __restrict__ f3) {
  fin_dev<64,128,16,512>(ym, yn, pp1, g3, be3, f3, blockIdx.x);
}

__global__ __launch_bounds__(256) void knn4_kernel(const float* __restrict__ cq2,
    const float* __restrict__ cq1, u64* __restrict__ part) {
  knn_part_dev(cq2, 128, cq1, 512, 8, part, blockIdx.x);
}

__global__ __launch_bounds__(256) void conv4_kernel(const float* __restrict__ f3,
    const float* __restrict__ fq2, const u64* __restrict__ part,
    const float* __restrict__ w4, float* __restrict__ ym, float* __restrict__ yn,
    double2* __restrict__ pp1) {
  conv_dev<64,128,2,8,64>(f3, 512, fq2, 128, part, w4, ym, yn, pp1, blockIdx.x);
}

__global__ __launch_bounds__(256) void fin4_kernel(const float* __restrict__ ym,
    const float* __restrict__ yn, const double2* __restrict__ pp1,
    const float* __restrict__ g4, const float* __restrict__ be4,
    float* __restrict__ f4) {
  fin_dev<128,64,8,128>(ym, yn, pp1, g4, be4, f4, blockIdx.x);
}

extern "C" void kernel_launch(void* const* d_in, const int* in_sizes, int n_in,
                              void* d_out, int out_size, void* d_ws, size_t ws_size,
                              hipStream_t stream) {
  const float* x    = (const float*)d_in[0];
  const float* w_in = (const float*)d_in[3];
  const float* b_in = (const float*)d_in[4];
  const float* w1 = (const float*)d_in[5];
  const float* g1 = (const float*)d_in[6];
  const float* be1= (const float*)d_in[7];
  const float* w2 = (const float*)d_in[8];
  const float* g2 = (const float*)d_in[9];
  const float* be2= (const float*)d_in[10];
  const float* w3 = (const float*)d_in[11];
  const float* g3 = (const float*)d_in[12];
  const float* be3= (const float*)d_in[13];
  const float* w4 = (const float*)d_in[14];
  const float* g4 = (const float*)d_in[15];
  const float* be4= (const float*)d_in[16];
  float* out = (float*)d_out;
  (void)in_sizes; (void)n_in; (void)out_size; (void)ws_size;

  char* ws = (char*)d_ws;
  size_t off = 0;
  auto alloc = [&](size_t count) {        // count in 4-byte units
    void* p = ws + off;
    off += (count * 4 + 255) & ~(size_t)255;
    return p;
  };
  float* f0    = (float*)alloc(16*2048*8);
  float* f1    = (float*)alloc(16*2048*32);
  float* f2    = (float*)alloc(16*512*64);
  float* f3    = (float*)alloc(16*512*64);
  float* fq1   = (float*)alloc(16*512*32);
  float* fq2   = (float*)alloc(16*128*64);
  float* cq1   = (float*)alloc(16*512*3);
  float* ym    = (float*)alloc(16*2048*32);
  float* yn    = (float*)alloc(16*2048*32);
  double2* pp1 = (double2*)alloc(16*256*4*4);     // 16384 double2
  int* fidx1   = (int*)alloc(16*512);
  int* fidx2   = (int*)alloc(16*128);
  float* g_dl1 = (float*)alloc(16*2048);
  int* g_far1  = (int*)alloc(16);
  float* g_dl2 = (float*)alloc(16*512);
  int* g_far2  = (int*)alloc(16);
  u64* part    = (u64*)alloc(2 * 16*2048*4*16);   // 16 MB (2M u64)
  u64* partB   = part + (size_t)16*512*8*16;      // 8 MB offset for knn3

  float* cq2 = out;              // (16,128,3)
  float* f4  = out + 16*128*3;   // (16,128,128)

  // ---- layer 1: knn1(KC=4) + f0, fps1 riding all three dispatches ----
  fusedA_kernel<<<656, 256, 0, stream>>>(x, w_in, b_in, f0, part, fidx1, g_dl1, g_far1);
  conv1_kernel<<<4112, 256, 0, stream>>>(x, fidx1, g_dl1, g_far1, f0, part, w1, ym, yn, pp1);
  fin1_kernel<<<528, 256, 0, stream>>>(x, fidx1, g_dl1, g_far1, ym, yn, pp1, g1, be1, f1);
  gather_kernel<<<32, 256, 0, stream>>>(x, f1, 2048, 32, fidx1, 512, cq1, fq1);

  // ---- layers 2+3 knn + fps2 ----
  fusedB_kernel<<<528, 256, 0, stream>>>(cq1, x, part, partB, fidx2, g_dl2, g_far2);
  conv2_kernel<<<2064, 256, 0, stream>>>(cq1, fidx2, g_dl2, g_far2, f1, fq1, part, w2, ym, yn, pp1);
  fin2_kernel<<<256, 256, 0, stream>>>(ym, yn, pp1, g2, be2, f2);

  // ---- layer 3 ----
  conv3_kernel<<<2048, 256, 0, stream>>>(f2, partB, w3, ym, yn, pp1);
  fin3_kernel<<<256, 256, 0, stream>>>(ym, yn, pp1, g3, be3, f3);
  gather_kernel<<<8, 256, 0, stream>>>(cq1, f3, 512, 64, fidx2, 128, cq2, fq2);

  // ---- layer 4 ----
  knn4_kernel<<<128, 256, 0, stream>>>(cq2, cq1, part);
  conv4_kernel<<<1024, 256, 0, stream>>>(f3, fq2, part, w4, ym, yn, pp1);
  fin4_kernel<<<128, 256, 0, stream>>>(ym, yn, pp1, g4, be4, f4);
}